// Round 8
// baseline (373.342 us; speedup 1.0000x reference)
//
#include <hip/hip_runtime.h>
#include <math.h>

#define N_NODES 100000
#define N_EDGES 1600000
#define DIM     128
#define NCLS    40
#define NBUCK   391      // 256-dst buckets = ceil(100000/256) == edge-chunk count
#define P1_CH   4096     // edges per chunk
#define CAPB    32       // per-(block,bucket) sub-slot capacity (mean 10.5, sigma 3.2; P(>=33)~1e-12)

typedef _Float16 f16x8 __attribute__((ext_vector_type(8)));
typedef _Float16 f16x2 __attribute__((ext_vector_type(2)));
typedef float    f32x4 __attribute__((ext_vector_type(4)));

__device__ inline unsigned short f16bits(float f) {
    union { _Float16 h; unsigned short u; } cv;
    cv.h = (_Float16)f;
    return cv.u;
}
__device__ inline f16x2 as_h2(unsigned u) {
    union { unsigned u; f16x2 h; } cv;
    cv.u = u;
    return cv.h;
}
__device__ inline unsigned as_u(f16x2 h) {
    union { f16x2 h; unsigned u; } cv;
    cv.h = h;
    return cv.u;
}
__device__ inline unsigned pack_h2(float lo, float hi) {
    f16x2 h;
    h.x = (_Float16)lo;
    h.y = (_Float16)hi;
    return as_u(h);
}
__device__ inline int wave_incl_scan(int v, int lane) {
#pragma unroll
    for (int off = 1; off < 64; off <<= 1) {
        int x = __shfl_up(v, off, 64);
        if (lane >= off) v += x;
    }
    return v;
}

// ---------------------------------------------------------------- setup + phase-1 bucketing (ZERO global atomics)
// blocks 0..191: W swizzles; 192..215: Wc swizzle; 216: H2 pad zero;
// 217..607: chunk k buckets its 4096 edges into fixed sub-slots
// tmp[(b*NBUCK + k)*CAPB + r] and writes cntmat[b][k] = count.
__global__ __launch_bounds__(256) void setup_p1(const float* __restrict__ W0,
                                                const float* __restrict__ W1,
                                                const float* __restrict__ W2,
                                                const float* __restrict__ Wc,
                                                const int* __restrict__ ei,
                                                unsigned short* __restrict__ Wsw0,
                                                unsigned short* __restrict__ Wsw1,
                                                unsigned short* __restrict__ Wsw2,
                                                unsigned short* __restrict__ Wcsw,
                                                int* __restrict__ cntmat,
                                                unsigned* __restrict__ tmp,
                                                unsigned short* __restrict__ H2) {
    const int blk = blockIdx.x;
    const int t   = threadIdx.x;

    if (blk < 192) {
        const float* W = (blk < 64) ? W0 : (blk < 128) ? W1 : W2;
        unsigned short* Wsw = (blk < 64) ? Wsw0 : (blk < 128) ? Wsw1 : Wsw2;
        int o = (blk & 63) * 256 + t;  // 0..16383
        int f = o >> 9;
        int l = (o >> 3) & 63;
        int j = o & 7;
        int n = f >> 2;
        int s = f & 3;
        int k = s * 32 + (l >> 4) * 8 + j;
        int c = (l & 15) * 8 + n;
        Wsw[o] = f16bits(W[k * DIM + c]);
        return;
    }
    if (blk < 216) {
        int o = (blk - 192) * 256 + t; // 0..6143
        int f = o >> 9;
        int l = (o >> 3) & 63;
        int j = o & 7;
        int n = f >> 2;
        int s = f & 3;
        int k = s * 32 + (l >> 4) * 8 + j;
        int c = (l & 15) * 3 + n;
        Wcsw[o] = (c < NCLS) ? f16bits(Wc[k * NCLS + c]) : (unsigned short)0;
        return;
    }
    if (blk == 216) {
        // zero H2 pad rows (gather sentinel target): rows N..N+31
        uint4* p = (uint4*)(H2 + (size_t)N_NODES * DIM);
        uint4 zz = make_uint4(0u, 0u, 0u, 0u);
#pragma unroll
        for (int i = 0; i < 4; ++i) p[t + i * 256] = zz;
        return;
    }

    // ---- phase-1 bucketing (chunk k) ----
    __shared__ int  hist[512];
    __shared__ int  lscan[512];
    __shared__ int  rank_[512];
    __shared__ int  wtA[4];
    __shared__ int2 stage[P1_CH];      // 32 KB

    const int lane = t & 63, wv = t >> 6;
    const int k   = blk - 217;         // chunk id == src-block id, 0..390
    const int e0  = k * P1_CH;
    const int cnt = min(P1_CH, N_EDGES - e0);

    hist[t] = 0;
    hist[t + 256] = 0;
    __syncthreads();

    int2 ed[16];
#pragma unroll
    for (int i = 0; i < 16; ++i) {
        int idx = t + i * 256;
        if (idx < cnt) {
            ed[i] = make_int2(ei[e0 + idx], ei[N_EDGES + e0 + idx]);
            atomicAdd(&hist[ed[i].y >> 8], 1);
        }
    }
    __syncthreads();

    // 512-wide local scan (2/thread); publish per-(bucket,block) counts non-atomically
    int h0 = hist[2 * t], h1 = hist[2 * t + 1];
    int pvA = h0 + h1;
    int iA = wave_incl_scan(pvA, lane);
    if (lane == 63) wtA[wv] = iA;
    __syncthreads();
    {
        int fA = 0;
        for (int i = 0; i < wv; ++i) fA += wtA[i];
        iA += fA;
    }
    int eA = iA - pvA;
    lscan[2 * t]     = eA;
    lscan[2 * t + 1] = eA + h0;
    rank_[2 * t]     = eA;
    rank_[2 * t + 1] = eA + h0;
    if (2 * t < NBUCK)     cntmat[(size_t)(2 * t) * NBUCK + k]     = h0;
    if (2 * t + 1 < NBUCK) cntmat[(size_t)(2 * t + 1) * NBUCK + k] = h1;
    __syncthreads();

#pragma unroll
    for (int i = 0; i < 16; ++i) {
        int idx = t + i * 256;
        if (idx < cnt) {
            int b = ed[i].y >> 8;
            int p = atomicAdd(&rank_[b], 1);      // LDS atomic (in-block, cheap)
            stage[p] = ed[i];
        }
    }
    __syncthreads();

    for (int p = t; p < cnt; p += 256) {
        int2 v = stage[p];
        int b = v.y >> 8;
        int r = p - lscan[b];                     // local rank within (b,k)
        if (r < CAPB)                             // clamp (P ~1e-12; keeps memory safe)
            tmp[((size_t)b * NBUCK + k) * CAPB + r] = ((unsigned)v.x << 8) | ((unsigned)v.y & 255u);
    }
}

// ---------------------------------------------------------------- bucket totals: one wave per bucket, zero atomics
__global__ __launch_bounds__(256) void bsum(const int* __restrict__ cntmat,
                                            int* __restrict__ bcnt) {
    const int gw   = (blockIdx.x * 256 + threadIdx.x) >> 6;  // global wave id 0..511
    const int lane = threadIdx.x & 63;
    int s = 0;
    if (gw < NBUCK) {
        const int* row = cntmat + (size_t)gw * NBUCK;
        for (int i = lane; i < NBUCK; i += 64) s += row[i];
#pragma unroll
        for (int m = 1; m < 64; m <<= 1) s += __shfl_xor(s, m, 64);
    }
    if (gw < 512 && lane == 0) bcnt[gw] = s;     // zeros for gw in [NBUCK,512)
}

// ---------------------------------------------------------------- phase-2 CSR + fused LAYER-0 GEMM (zero global atomics)
// Block b: read cntmat row b (validity), scan bcnt for global base, build
// rowptr/dinv/rec from tmp sub-slots; then GEMM X rows b*256..+255 with W0.
__global__ __launch_bounds__(256) void csr_p2_gemm(const unsigned* __restrict__ tmp,
                                                   const int* __restrict__ cntmat,
                                                   const int* __restrict__ bcnt,
                                                   const float* __restrict__ X,
                                                   const unsigned short* __restrict__ Wsw,
                                                   int* __restrict__ rowptr,
                                                   float* __restrict__ dinv,
                                                   unsigned* __restrict__ rec,
                                                   unsigned short* __restrict__ H) {
    __shared__ unsigned short wlds[32 * 512];   // 32 KB
    __shared__ int   cnts[512];                 // per-src-block counts for this bucket
    __shared__ int   cnt2[256];
    __shared__ int   cur[256];
    __shared__ float dv_s[256];
    __shared__ int   wt[4];
    __shared__ int   sbeg_s;
    const int t = threadIdx.x;
    const int lane = t & 63, wv = t >> 6;
    const int b = blockIdx.x;

    // stage W0 (independent of CSR work)
    {
        const uint4* srcp = (const uint4*)Wsw;
        uint4*       dstp = (uint4*)wlds;
#pragma unroll
        for (int i = 0; i < 8; ++i) dstp[t + i * 256] = srcp[t + i * 256];
    }

    // this bucket's per-src-block counts (row b of cntmat)
    cnts[t]       = (t < NBUCK)       ? cntmat[(size_t)b * NBUCK + t]       : 0;
    cnts[t + 256] = (t + 256 < NBUCK) ? cntmat[(size_t)b * NBUCK + t + 256] : 0;

    // global bucket-base scan over bcnt (512-wide, zeros past NBUCK)
    int v0 = bcnt[2 * t], v1 = bcnt[2 * t + 1];
    int pv = v0 + v1;
    int incl = wave_incl_scan(pv, lane);
    if (lane == 63) wt[wv] = incl;
    cnt2[t] = 0;
    __syncthreads();
    {
        int pf = 0;
        for (int i = 0; i < wv; ++i) pf += wt[i];
        incl += pf;
        int eB = incl - pv;
        if (2 * t == b)     sbeg_s = eB;
        if (2 * t + 1 == b) sbeg_s = eB + v0;
    }
    __syncthreads();

    // pass 1: histogram of dst&255 over valid sub-slot entries
    const unsigned* tb = tmp + (size_t)b * (NBUCK * CAPB);
    for (int s = t; s < NBUCK * CAPB; s += 256) {
        if ((s & (CAPB - 1)) < cnts[s >> 5])
            atomicAdd(&cnt2[tb[s] & 255u], 1);
    }
    __syncthreads();

    int c = cnt2[t];
    int incl2 = wave_incl_scan(c, lane);
    if (lane == 63) wt[wv] = incl2;
    __syncthreads();
    {
        int pf = 0;
        for (int i = 0; i < wv; ++i) pf += wt[i];
        incl2 += pf;
    }
    int rb = sbeg_s + (incl2 - c);
    cur[t] = rb;
    float dv = rsqrtf((float)c + 1.0f);
    dv_s[t] = dv;
    const int node = (b << 8) + t;
    if (node < N_NODES) {
        rowptr[node] = rb;
        dinv[node]   = dv;
    }
    if (b == NBUCK - 1 && t == 0) rowptr[N_NODES] = N_EDGES;
    __syncthreads();

    // pass 2: scatter rec (LDS cur atomics only)
    for (int s = t; s < NBUCK * CAPB; s += 256) {
        if ((s & (CAPB - 1)) < cnts[s >> 5]) {
            unsigned u = tb[s];
            int pos = atomicAdd(&cur[u & 255u], 1);
            if ((unsigned)pos < (unsigned)N_EDGES)
                rec[pos] = (u >> 8) << 8;         // src byte-offset
        }
    }

    // ---- fused layer-0 GEMM: 256 rows of this block, 4 row-tiles per wave ----
    const int mq = lane & 15;
    const int q  = lane >> 4;
    const int rowbase = (b << 8) + wv * 64;

    for (int r4 = 0; r4 < 4; ++r4) {
        const int row0 = rowbase + r4 * 16;
        int r = row0 + mq;
        if (r >= N_NODES) r = N_NODES - 1;
        const float* xp = X + (size_t)r * DIM + q * 8;
        f16x8 af[4];
#pragma unroll
        for (int s = 0; s < 4; ++s) {
            float4 x0 = *(const float4*)(xp + s * 32);
            float4 x1 = *(const float4*)(xp + s * 32 + 4);
            f16x8 v;
            v[0] = (_Float16)x0.x; v[1] = (_Float16)x0.y;
            v[2] = (_Float16)x0.z; v[3] = (_Float16)x0.w;
            v[4] = (_Float16)x1.x; v[5] = (_Float16)x1.y;
            v[6] = (_Float16)x1.z; v[7] = (_Float16)x1.w;
            af[s] = v;
        }

        f32x4 acc[8];
        f32x4 z = {0.f, 0.f, 0.f, 0.f};
#pragma unroll
        for (int n = 0; n < 8; ++n) acc[n] = z;

        const unsigned short* wl = wlds + lane * 8;
#pragma unroll
        for (int s = 0; s < 4; ++s)
#pragma unroll
            for (int n = 0; n < 8; ++n) {
                f16x8 wf = *(const f16x8*)(wl + ((n * 4 + s) << 9));
                acc[n] = __builtin_amdgcn_mfma_f32_16x16x32_f16(af[s], wf, acc[n], 0, 0, 0);
            }

#pragma unroll
        for (int j = 0; j < 4; ++j) {
            int row = row0 + q * 4 + j;
            if (row < N_NODES) {
                float dvr = dv_s[row - (b << 8)];
                uint4 o;
                o.x = pack_h2(acc[0][j] * dvr, acc[1][j] * dvr);
                o.y = pack_h2(acc[2][j] * dvr, acc[3][j] * dvr);
                o.z = pack_h2(acc[4][j] * dvr, acc[5][j] * dvr);
                o.w = pack_h2(acc[6][j] * dvr, acc[7][j] * dvr);
                *(uint4*)(H + (size_t)row * DIM + mq * 8) = o;
            } else if (row < N_NODES + 32) {
                uint4 zz = make_uint4(0u, 0u, 0u, 0u);   // zero pad rows (gather sentinel)
                *(uint4*)(H + (size_t)row * DIM + mq * 8) = zz;
            }
        }
    }
}

// ---------------------------------------------------------------- fused agg + LN + ELU (+resid) + NEXT-LAYER GEMM
__global__ __launch_bounds__(256) void agg_ln_gemm(const unsigned short* __restrict__ Hh,
                                                   const unsigned short* __restrict__ xin,
                                                   const float* __restrict__ dinv,
                                                   const float* __restrict__ bias,
                                                   const float* __restrict__ g,
                                                   const float* __restrict__ be,
                                                   const int* __restrict__ rowptr,
                                                   const unsigned* __restrict__ rec,
                                                   const unsigned short* __restrict__ Wsw,
                                                   unsigned short* __restrict__ Cout,
                                                   unsigned short* __restrict__ Hout) {
    __shared__ _Float16 hl[16][136];
    const int tid  = threadIdx.x;
    const int lane = tid & 63;
    const int l16  = tid & 15;
    const int gb   = lane & 48;
    const int grp  = tid >> 4;
    const int wave = tid >> 6;
    const int node0 = blockIdx.x * 16;
    const int node = node0 + grp;
    const int beg  = rowptr[node];
    const int end  = rowptr[node + 1];
    const char* Hb8 = (const char*)Hh;
    const unsigned laneoff = (unsigned)l16 * 16;
    const unsigned sentin  = (unsigned)N_NODES << 8;

    f16x2 accA[4], accB[4], accC[4], accD[4];
    f16x2 hz = {(_Float16)0.f, (_Float16)0.f};
#pragma unroll
    for (int k = 0; k < 4; ++k) { accA[k] = hz; accB[k] = hz; accC[k] = hz; accD[k] = hz; }

    for (int e0 = beg; e0 < end; e0 += 16) {
        int cnt = min(end - e0, 16);
        unsigned sv = (l16 < cnt) ? rec[e0 + l16] : sentin;
        int cntR = (cnt + 7) & ~7;
        for (int j = 0; j < cntR; j += 8) {
            unsigned o0 = (unsigned)__shfl((int)sv, gb + j + 0, 64) + laneoff;
            unsigned o1 = (unsigned)__shfl((int)sv, gb + j + 1, 64) + laneoff;
            unsigned o2 = (unsigned)__shfl((int)sv, gb + j + 2, 64) + laneoff;
            unsigned o3 = (unsigned)__shfl((int)sv, gb + j + 3, 64) + laneoff;
            unsigned o4 = (unsigned)__shfl((int)sv, gb + j + 4, 64) + laneoff;
            unsigned o5 = (unsigned)__shfl((int)sv, gb + j + 5, 64) + laneoff;
            unsigned o6 = (unsigned)__shfl((int)sv, gb + j + 6, 64) + laneoff;
            unsigned o7 = (unsigned)__shfl((int)sv, gb + j + 7, 64) + laneoff;
            uint4 u0 = *(const uint4*)(Hb8 + o0);
            uint4 u1 = *(const uint4*)(Hb8 + o1);
            uint4 u2 = *(const uint4*)(Hb8 + o2);
            uint4 u3 = *(const uint4*)(Hb8 + o3);
            uint4 u4 = *(const uint4*)(Hb8 + o4);
            uint4 u5 = *(const uint4*)(Hb8 + o5);
            uint4 u6 = *(const uint4*)(Hb8 + o6);
            uint4 u7 = *(const uint4*)(Hb8 + o7);
            accA[0] += as_h2(u0.x); accA[1] += as_h2(u0.y); accA[2] += as_h2(u0.z); accA[3] += as_h2(u0.w);
            accB[0] += as_h2(u1.x); accB[1] += as_h2(u1.y); accB[2] += as_h2(u1.z); accB[3] += as_h2(u1.w);
            accC[0] += as_h2(u2.x); accC[1] += as_h2(u2.y); accC[2] += as_h2(u2.z); accC[3] += as_h2(u2.w);
            accD[0] += as_h2(u3.x); accD[1] += as_h2(u3.y); accD[2] += as_h2(u3.z); accD[3] += as_h2(u3.w);
            accA[0] += as_h2(u4.x); accA[1] += as_h2(u4.y); accA[2] += as_h2(u4.z); accA[3] += as_h2(u4.w);
            accB[0] += as_h2(u5.x); accB[1] += as_h2(u5.y); accB[2] += as_h2(u5.z); accB[3] += as_h2(u5.w);
            accC[0] += as_h2(u6.x); accC[1] += as_h2(u6.y); accC[2] += as_h2(u6.z); accC[3] += as_h2(u6.w);
            accD[0] += as_h2(u7.x); accD[1] += as_h2(u7.y); accD[2] += as_h2(u7.z); accD[3] += as_h2(u7.w);
        }
    }

#pragma unroll
    for (int k = 0; k < 4; ++k) accA[k] = (accA[k] + accB[k]) + (accC[k] + accD[k]);

    const float dv = dinv[node];
    const unsigned nodeoff = ((unsigned)node << 8) + laneoff;
    uint4 hv = *(const uint4*)(Hb8 + nodeoff);       // h'[node] (pre-scaled)
    const int c0 = l16 * 8;
    float4 bb0 = *(const float4*)(bias + c0);
    float4 bb1 = *(const float4*)(bias + c0 + 4);
    f16x2 h0 = as_h2(hv.x), h1 = as_h2(hv.y), h2 = as_h2(hv.z), h3 = as_h2(hv.w);

    float a[8];
    a[0] = ((float)accA[0].x + (float)h0.x) * dv + bb0.x;
    a[1] = ((float)accA[0].y + (float)h0.y) * dv + bb0.y;
    a[2] = ((float)accA[1].x + (float)h1.x) * dv + bb0.z;
    a[3] = ((float)accA[1].y + (float)h1.y) * dv + bb0.w;
    a[4] = ((float)accA[2].x + (float)h2.x) * dv + bb1.x;
    a[5] = ((float)accA[2].y + (float)h2.y) * dv + bb1.y;
    a[6] = ((float)accA[3].x + (float)h3.x) * dv + bb1.z;
    a[7] = ((float)accA[3].y + (float)h3.y) * dv + bb1.w;

    float s1 = 0.f, s2 = 0.f;
#pragma unroll
    for (int i = 0; i < 8; ++i) { s1 += a[i]; s2 += a[i] * a[i]; }
#pragma unroll
    for (int mk = 1; mk <= 8; mk <<= 1) {
        s1 += __shfl_xor(s1, mk, 64);
        s2 += __shfl_xor(s2, mk, 64);
    }
    float mean = s1 * (1.0f / 128.0f);
    float var  = s2 * (1.0f / 128.0f) - mean * mean;
    float rr   = rsqrtf(var + 1e-5f);

    float4 gg0 = *(const float4*)(g + c0);
    float4 gg1 = *(const float4*)(g + c0 + 4);
    float4 ee0 = *(const float4*)(be + c0);
    float4 ee1 = *(const float4*)(be + c0 + 4);

    float r[8];
    r[0] = (a[0] - mean) * rr * gg0.x + ee0.x;
    r[1] = (a[1] - mean) * rr * gg0.y + ee0.y;
    r[2] = (a[2] - mean) * rr * gg0.z + ee0.z;
    r[3] = (a[3] - mean) * rr * gg0.w + ee0.w;
    r[4] = (a[4] - mean) * rr * gg1.x + ee1.x;
    r[5] = (a[5] - mean) * rr * gg1.y + ee1.y;
    r[6] = (a[6] - mean) * rr * gg1.z + ee1.z;
    r[7] = (a[7] - mean) * rr * gg1.w + ee1.w;
#pragma unroll
    for (int i = 0; i < 8; ++i) r[i] = r[i] > 0.0f ? r[i] : expm1f(r[i]);

    if (xin) {
        uint4 xv = *(const uint4*)((const char*)xin + nodeoff);
        f16x2 x0 = as_h2(xv.x), x1 = as_h2(xv.y), x2 = as_h2(xv.z), x3 = as_h2(xv.w);
        r[0] += (float)x0.x; r[1] += (float)x0.y;
        r[2] += (float)x1.x; r[3] += (float)x1.y;
        r[4] += (float)x2.x; r[5] += (float)x2.y;
        r[6] += (float)x3.x; r[7] += (float)x3.y;
    }

    uint4 o;
    o.x = pack_h2(r[0], r[1]);
    o.y = pack_h2(r[2], r[3]);
    o.z = pack_h2(r[4], r[5]);
    o.w = pack_h2(r[6], r[7]);
    *(uint4*)((char*)Cout + nodeoff) = o;        // residual source for next layer
    *(uint4*)&hl[grp][l16 * 8] = o;              // GEMM A-tile
    __syncthreads();

    // ---- next-layer GEMM: 16x128 tile, 2 col-tiles per wave ----
    {
        const int m = lane & 15;
        const int q = lane >> 4;

        f16x8 af[4];
#pragma unroll
        for (int s = 0; s < 4; ++s)
            af[s] = *(const f16x8*)&hl[m][q * 8 + s * 32];

        f32x4 acc2[2];
        f32x4 z = {0.f, 0.f, 0.f, 0.f};
        acc2[0] = z; acc2[1] = z;

#pragma unroll
        for (int s = 0; s < 4; ++s)
#pragma unroll
            for (int p = 0; p < 2; ++p) {
                f16x8 wfv = *(const f16x8*)(Wsw + (((2 * wave + p) * 4 + s) << 9) + lane * 8);
                acc2[p] = __builtin_amdgcn_mfma_f32_16x16x32_f16(af[s], wfv, acc2[p], 0, 0, 0);
            }

#pragma unroll
        for (int j = 0; j < 4; ++j) {
            int row = node0 + q * 4 + j;
            float dv2 = dinv[row];
            *(unsigned*)((char*)Hout + ((unsigned)row << 8) + ((unsigned)(m * 8 + 2 * wave) << 1)) =
                pack_h2(acc2[0][j] * dv2, acc2[1][j] * dv2);
        }
    }
}

// ---------------------------------------------------------------- layer-2 agg + LN + ELU + residual + CLASSIFIER (fused)
__global__ __launch_bounds__(256) void agg_ln_cls(const unsigned short* __restrict__ Hh,
                                                  const unsigned short* __restrict__ xin,
                                                  const float* __restrict__ dinv,
                                                  const float* __restrict__ bias,
                                                  const float* __restrict__ g,
                                                  const float* __restrict__ be,
                                                  const int* __restrict__ rowptr,
                                                  const unsigned* __restrict__ rec,
                                                  const unsigned short* __restrict__ Wcsw,
                                                  const float* __restrict__ bc,
                                                  float* __restrict__ out) {
    __shared__ _Float16 hl[16][136];
    const int tid  = threadIdx.x;
    const int lane = tid & 63;
    const int l16  = tid & 15;
    const int gb   = lane & 48;
    const int grp  = tid >> 4;
    const int node0 = blockIdx.x * 16;
    const int node = node0 + grp;
    const int beg  = rowptr[node];
    const int end  = rowptr[node + 1];
    const char* Hb8 = (const char*)Hh;
    const unsigned laneoff = (unsigned)l16 * 16;
    const unsigned sentin  = (unsigned)N_NODES << 8;

    f16x2 accA[4], accB[4], accC[4], accD[4];
    f16x2 hz = {(_Float16)0.f, (_Float16)0.f};
#pragma unroll
    for (int k = 0; k < 4; ++k) { accA[k] = hz; accB[k] = hz; accC[k] = hz; accD[k] = hz; }

    for (int e0 = beg; e0 < end; e0 += 16) {
        int cnt = min(end - e0, 16);
        unsigned sv = (l16 < cnt) ? rec[e0 + l16] : sentin;
        int cntR = (cnt + 7) & ~7;
        for (int j = 0; j < cntR; j += 8) {
            unsigned o0 = (unsigned)__shfl((int)sv, gb + j + 0, 64) + laneoff;
            unsigned o1 = (unsigned)__shfl((int)sv, gb + j + 1, 64) + laneoff;
            unsigned o2 = (unsigned)__shfl((int)sv, gb + j + 2, 64) + laneoff;
            unsigned o3 = (unsigned)__shfl((int)sv, gb + j + 3, 64) + laneoff;
            unsigned o4 = (unsigned)__shfl((int)sv, gb + j + 4, 64) + laneoff;
            unsigned o5 = (unsigned)__shfl((int)sv, gb + j + 5, 64) + laneoff;
            unsigned o6 = (unsigned)__shfl((int)sv, gb + j + 6, 64) + laneoff;
            unsigned o7 = (unsigned)__shfl((int)sv, gb + j + 7, 64) + laneoff;
            uint4 u0 = *(const uint4*)(Hb8 + o0);
            uint4 u1 = *(const uint4*)(Hb8 + o1);
            uint4 u2 = *(const uint4*)(Hb8 + o2);
            uint4 u3 = *(const uint4*)(Hb8 + o3);
            uint4 u4 = *(const uint4*)(Hb8 + o4);
            uint4 u5 = *(const uint4*)(Hb8 + o5);
            uint4 u6 = *(const uint4*)(Hb8 + o6);
            uint4 u7 = *(const uint4*)(Hb8 + o7);
            accA[0] += as_h2(u0.x); accA[1] += as_h2(u0.y); accA[2] += as_h2(u0.z); accA[3] += as_h2(u0.w);
            accB[0] += as_h2(u1.x); accB[1] += as_h2(u1.y); accB[2] += as_h2(u1.z); accB[3] += as_h2(u1.w);
            accC[0] += as_h2(u2.x); accC[1] += as_h2(u2.y); accC[2] += as_h2(u2.z); accC[3] += as_h2(u2.w);
            accD[0] += as_h2(u3.x); accD[1] += as_h2(u3.y); accD[2] += as_h2(u3.z); accD[3] += as_h2(u3.w);
            accA[0] += as_h2(u4.x); accA[1] += as_h2(u4.y); accA[2] += as_h2(u4.z); accA[3] += as_h2(u4.w);
            accB[0] += as_h2(u5.x); accB[1] += as_h2(u5.y); accB[2] += as_h2(u5.z); accB[3] += as_h2(u5.w);
            accC[0] += as_h2(u6.x); accC[1] += as_h2(u6.y); accC[2] += as_h2(u6.z); accC[3] += as_h2(u6.w);
            accD[0] += as_h2(u7.x); accD[1] += as_h2(u7.y); accD[2] += as_h2(u7.z); accD[3] += as_h2(u7.w);
        }
    }

#pragma unroll
    for (int k = 0; k < 4; ++k) accA[k] = (accA[k] + accB[k]) + (accC[k] + accD[k]);

    const float dv = dinv[node];
    const unsigned nodeoff = ((unsigned)node << 8) + laneoff;
    uint4 hv = *(const uint4*)(Hb8 + nodeoff);
    const int c0 = l16 * 8;
    float4 bb0 = *(const float4*)(bias + c0);
    float4 bb1 = *(const float4*)(bias + c0 + 4);
    f16x2 h0 = as_h2(hv.x), h1 = as_h2(hv.y), h2 = as_h2(hv.z), h3 = as_h2(hv.w);

    float a[8];
    a[0] = ((float)accA[0].x + (float)h0.x) * dv + bb0.x;
    a[1] = ((float)accA[0].y + (float)h0.y) * dv + bb0.y;
    a[2] = ((float)accA[1].x + (float)h1.x) * dv + bb0.z;
    a[3] = ((float)accA[1].y + (float)h1.y) * dv + bb0.w;
    a[4] = ((float)accA[2].x + (float)h2.x) * dv + bb1.x;
    a[5] = ((float)accA[2].y + (float)h2.y) * dv + bb1.y;
    a[6] = ((float)accA[3].x + (float)h3.x) * dv + bb1.z;
    a[7] = ((float)accA[3].y + (float)h3.y) * dv + bb1.w;

    float s1 = 0.f, s2 = 0.f;
#pragma unroll
    for (int i = 0; i < 8; ++i) { s1 += a[i]; s2 += a[i] * a[i]; }
#pragma unroll
    for (int mk = 1; mk <= 8; mk <<= 1) {
        s1 += __shfl_xor(s1, mk, 64);
        s2 += __shfl_xor(s2, mk, 64);
    }
    float mean = s1 * (1.0f / 128.0f);
    float var  = s2 * (1.0f / 128.0f) - mean * mean;
    float rr   = rsqrtf(var + 1e-5f);

    float4 gg0 = *(const float4*)(g + c0);
    float4 gg1 = *(const float4*)(g + c0 + 4);
    float4 ee0 = *(const float4*)(be + c0);
    float4 ee1 = *(const float4*)(be + c0 + 4);

    float r[8];
    r[0] = (a[0] - mean) * rr * gg0.x + ee0.x;
    r[1] = (a[1] - mean) * rr * gg0.y + ee0.y;
    r[2] = (a[2] - mean) * rr * gg0.z + ee0.z;
    r[3] = (a[3] - mean) * rr * gg0.w + ee0.w;
    r[4] = (a[4] - mean) * rr * gg1.x + ee1.x;
    r[5] = (a[5] - mean) * rr * gg1.y + ee1.y;
    r[6] = (a[6] - mean) * rr * gg1.z + ee1.z;
    r[7] = (a[7] - mean) * rr * gg1.w + ee1.w;
#pragma unroll
    for (int i = 0; i < 8; ++i) r[i] = r[i] > 0.0f ? r[i] : expm1f(r[i]);

    if (xin) {
        uint4 xv = *(const uint4*)((const char*)xin + nodeoff);
        f16x2 x0 = as_h2(xv.x), x1 = as_h2(xv.y), x2 = as_h2(xv.z), x3 = as_h2(xv.w);
        r[0] += (float)x0.x; r[1] += (float)x0.y;
        r[2] += (float)x1.x; r[3] += (float)x1.y;
        r[4] += (float)x2.x; r[5] += (float)x2.y;
        r[6] += (float)x3.x; r[7] += (float)x3.y;
    }

    uint4 o;
    o.x = pack_h2(r[0], r[1]);
    o.y = pack_h2(r[2], r[3]);
    o.z = pack_h2(r[4], r[5]);
    o.w = pack_h2(r[6], r[7]);
    *(uint4*)&hl[grp][l16 * 8] = o;
    __syncthreads();

    if (tid < 64) {
        const int m = lane & 15;
        const int q = lane >> 4;

        f16x8 wf[12];
#pragma unroll
        for (int f = 0; f < 12; ++f)
            wf[f] = *(const f16x8*)(Wcsw + (f << 9) + lane * 8);

        f16x8 af[4];
#pragma unroll
        for (int s = 0; s < 4; ++s)
            af[s] = *(const f16x8*)&hl[m][q * 8 + s * 32];

        f32x4 acc[3];
        f32x4 z = {0.f, 0.f, 0.f, 0.f};
#pragma unroll
        for (int n = 0; n < 3; ++n) acc[n] = z;

#pragma unroll
        for (int s = 0; s < 4; ++s)
#pragma unroll
            for (int n = 0; n < 3; ++n)
                acc[n] = __builtin_amdgcn_mfma_f32_16x16x32_f16(af[s], wf[n * 4 + s], acc[n], 0, 0, 0);

#pragma unroll
        for (int j = 0; j < 4; ++j) {
            int row = node0 + q * 4 + j;
#pragma unroll
            for (int n = 0; n < 3; ++n) {
                int c = 3 * m + n;
                if (c < NCLS)
                    out[(size_t)row * NCLS + c] = acc[n][j] + bc[c];
            }
        }
    }
}

// ---------------------------------------------------------------- launch
extern "C" void kernel_launch(void* const* d_in, const int* in_sizes, int n_in,
                              void* d_out, int out_size, void* d_ws, size_t ws_size,
                              hipStream_t stream) {
    const float* x  = (const float*)d_in[0];
    const int*   ei = (const int*)d_in[1];
    const float* W[3]  = {(const float*)d_in[2], (const float*)d_in[6], (const float*)d_in[10]};
    const float* b[3]  = {(const float*)d_in[3], (const float*)d_in[7], (const float*)d_in[11]};
    const float* g[3]  = {(const float*)d_in[4], (const float*)d_in[8], (const float*)d_in[12]};
    const float* be[3] = {(const float*)d_in[5], (const float*)d_in[9], (const float*)d_in[13]};
    const float* Wc = (const float*)d_in[14];
    const float* bc = (const float*)d_in[15];
    float* out = (float*)d_out;

    char* ws = (char*)d_ws;
    const size_t NP = 400128;  // padded (N+1)*4 bytes
    float* dinv   = (float*)(ws);
    int*   rowptr = (int*)  (ws + NP);
    int*   bcnt   = (int*)  (ws + 2 * NP);            // 512 ints (written by bsum, no memset)
    unsigned* rec = (unsigned*)(ws + 2 * NP + 4096);
    unsigned short* H1 = (unsigned short*)(ws + 2 * NP + 4096 + (size_t)N_EDGES * 8);
    unsigned short* H2 = H1 + (size_t)(N_NODES + 64) * DIM;   // both H buffers have zero-pad rows
    unsigned short* Ch = H2 + (size_t)(N_NODES + 64) * DIM;
    unsigned short* Wsw0 = Ch + (size_t)N_NODES * DIM;
    unsigned short* Wsw1 = Wsw0 + DIM * DIM;
    unsigned short* Wsw2 = Wsw1 + DIM * DIM;
    unsigned short* Wcsw = Wsw2 + DIM * DIM;          // 12*512 shorts
    int* cntmat = (int*)(Wcsw + 12 * 512);            // NBUCK*NBUCK ints = 612 KB
    unsigned* tmp = (unsigned*)Ch;                    // aliases Ch (19.6 MB < 25.6 MB); dead before agg0 writes Ch

    // ---- setup + p1 (deterministic sub-slot bucketing, zero global atomics) ----
    setup_p1<<<217 + NBUCK, 256, 0, stream>>>(W[0], W[1], W[2], Wc, ei,
                                              Wsw0, Wsw1, Wsw2, Wcsw, cntmat, tmp, H2);

    // ---- bucket totals (one wave per bucket) ----
    bsum<<<128, 256, 0, stream>>>(cntmat, bcnt);

    // ---- p2 CSR + fused layer-0 GEMM ----
    csr_p2_gemm<<<NBUCK, 256, 0, stream>>>(tmp, cntmat, bcnt, x, Wsw0, rowptr, dinv, rec, H1);

    const int agg_grid = N_NODES / 16;            // 6250 (16 nodes/block, quarter-wave each)

    // layer 0 agg + layer 1 GEMM: gather H1 -> Ch (residual), GEMM -> H2
    agg_ln_gemm<<<agg_grid, 256, 0, stream>>>(H1, nullptr, dinv, b[0], g[0], be[0],
                                              rowptr, rec, Wsw1, Ch, H2);

    // layer 1 agg + layer 2 GEMM: gather H2, resid Ch -> Ch (in-place), GEMM -> H1
    agg_ln_gemm<<<agg_grid, 256, 0, stream>>>(H2, Ch, dinv, b[1], g[1], be[1],
                                              rowptr, rec, Wsw2, Ch, H1);

    // layer 2 agg + classifier: gather H1, resid Ch -> logits
    agg_ln_cls<<<agg_grid, 256, 0, stream>>>(H1, Ch, dinv, b[2], g[2], be[2],
                                             rowptr, rec, Wcsw, bc, out);
}

// Round 10
// 363.355 us; speedup vs baseline: 1.0275x; 1.0275x over previous
//
#include <hip/hip_runtime.h>
#include <math.h>

#define N_NODES 100000
#define N_EDGES 1600000
#define DIM     128
#define NCLS    40
#define NBUCK   391      // 256-dst buckets = ceil(100000/256) == edge-chunk count
#define P1_CH   4096     // edges per chunk
#define CAP     8192     // fixed bucket capacity (expected 4096, sigma ~64)

typedef _Float16 f16x8 __attribute__((ext_vector_type(8)));
typedef _Float16 f16x2 __attribute__((ext_vector_type(2)));
typedef float    f32x4 __attribute__((ext_vector_type(4)));

__device__ inline unsigned short f16bits(float f) {
    union { _Float16 h; unsigned short u; } cv;
    cv.h = (_Float16)f;
    return cv.u;
}
__device__ inline f16x2 as_h2(unsigned u) {
    union { unsigned u; f16x2 h; } cv;
    cv.u = u;
    return cv.h;
}
__device__ inline unsigned as_u(f16x2 h) {
    union { f16x2 h; unsigned u; } cv;
    cv.h = h;
    return cv.u;
}
__device__ inline unsigned pack_h2(float lo, float hi) {
    f16x2 h;
    h.x = (_Float16)lo;
    h.y = (_Float16)hi;
    return as_u(h);
}
__device__ inline int wave_incl_scan(int v, int lane) {
#pragma unroll
    for (int off = 1; off < 64; off <<= 1) {
        int x = __shfl_up(v, off, 64);
        if (lane >= off) v += x;
    }
    return v;
}

// ---------------------------------------------------------------- setup + phase-1 bucketing (fixed-capacity, hardened)
// blocks 0..191: W swizzles; 192..215: Wc swizzle; 216: H2 pad zero;
// 217..607: bucket 4096 edges each into tmp[b*CAP + clamped atomic alloc].
__global__ __launch_bounds__(256) void setup_p1(const float* __restrict__ W0,
                                                const float* __restrict__ W1,
                                                const float* __restrict__ W2,
                                                const float* __restrict__ Wc,
                                                const int* __restrict__ ei,
                                                unsigned short* __restrict__ Wsw0,
                                                unsigned short* __restrict__ Wsw1,
                                                unsigned short* __restrict__ Wsw2,
                                                unsigned short* __restrict__ Wcsw,
                                                int* __restrict__ bcnt,
                                                unsigned* __restrict__ tmp,
                                                unsigned short* __restrict__ H2) {
    const int blk = blockIdx.x;
    const int t   = threadIdx.x;

    if (blk < 192) {
        const float* W = (blk < 64) ? W0 : (blk < 128) ? W1 : W2;
        unsigned short* Wsw = (blk < 64) ? Wsw0 : (blk < 128) ? Wsw1 : Wsw2;
        int o = (blk & 63) * 256 + t;  // 0..16383
        int f = o >> 9;
        int l = (o >> 3) & 63;
        int j = o & 7;
        int n = f >> 2;
        int s = f & 3;
        int k = s * 32 + (l >> 4) * 8 + j;
        int c = (l & 15) * 8 + n;
        Wsw[o] = f16bits(W[k * DIM + c]);
        return;
    }
    if (blk < 216) {
        int o = (blk - 192) * 256 + t; // 0..6143
        int f = o >> 9;
        int l = (o >> 3) & 63;
        int j = o & 7;
        int n = f >> 2;
        int s = f & 3;
        int k = s * 32 + (l >> 4) * 8 + j;
        int c = (l & 15) * 3 + n;
        Wcsw[o] = (c < NCLS) ? f16bits(Wc[k * NCLS + c]) : (unsigned short)0;
        return;
    }
    if (blk == 216) {
        // zero H2 pad rows (gather sentinel target): rows N..N+31
        uint4* p = (uint4*)(H2 + (size_t)N_NODES * DIM);
        uint4 zz = make_uint4(0u, 0u, 0u, 0u);
#pragma unroll
        for (int i = 0; i < 4; ++i) p[t + i * 256] = zz;
        return;
    }

    // ---- phase-1 bucketing ----
    __shared__ int  hist[512];
    __shared__ int  lscan[512];
    __shared__ int  rank_[512];
    __shared__ int  gbase[512];
    __shared__ int  wtA[4];
    __shared__ int2 stage[P1_CH];      // 32 KB

    const int lane = t & 63, wv = t >> 6;
    const int e0  = (blk - 217) * P1_CH;
    const int cnt = min(P1_CH, N_EDGES - e0);

    hist[t] = 0;
    hist[t + 256] = 0;
    __syncthreads();

    int2 ed[16];
#pragma unroll
    for (int i = 0; i < 16; ++i) {
        int idx = t + i * 256;
        if (idx < cnt) {
            ed[i] = make_int2(ei[e0 + idx], ei[N_EDGES + e0 + idx]);
            atomicAdd(&hist[ed[i].y >> 8], 1);
        }
    }
    __syncthreads();

    // 512-wide local scan (2/thread) + clamped fixed-cap global alloc
    int h0 = hist[2 * t], h1 = hist[2 * t + 1];
    int pvA = h0 + h1;
    int iA = wave_incl_scan(pvA, lane);
    if (lane == 63) wtA[wv] = iA;
    __syncthreads();
    {
        int fA = 0;
        for (int i = 0; i < wv; ++i) fA += wtA[i];
        iA += fA;
    }
    int eA = iA - pvA;
    lscan[2 * t]     = eA;
    lscan[2 * t + 1] = eA + h0;
    rank_[2 * t]     = eA;
    rank_[2 * t + 1] = eA + h0;
    if (h0) {
        int off = atomicAdd(&bcnt[2 * t], h0);
        if (off > CAP - h0) off = CAP - h0;           // clamp (never taken in practice)
        if (off < 0) off = 0;
        gbase[2 * t] = (2 * t) * CAP + off;
    }
    if (h1) {
        int off = atomicAdd(&bcnt[2 * t + 1], h1);
        if (off > CAP - h1) off = CAP - h1;
        if (off < 0) off = 0;
        gbase[2 * t + 1] = (2 * t + 1) * CAP + off;
    }
    __syncthreads();

#pragma unroll
    for (int i = 0; i < 16; ++i) {
        int idx = t + i * 256;
        if (idx < cnt) {
            int b = ed[i].y >> 8;
            int p = atomicAdd(&rank_[b], 1);
            stage[p] = ed[i];
        }
    }
    __syncthreads();

    for (int p = t; p < cnt; p += 256) {
        int2 v = stage[p];
        int b = v.y >> 8;
        int dstidx = gbase[b] + (p - lscan[b]);
        if (dstidx < (b + 1) * CAP)                   // hard bound: stay inside bucket slot
            tmp[dstidx] = ((unsigned)v.x << 8) | ((unsigned)v.y & 255u);
    }
}

// ---------------------------------------------------------------- phase-2 CSR + fused LAYER-0 GEMM (hardened)
__global__ __launch_bounds__(256) void csr_p2_gemm(const unsigned* __restrict__ tmp,
                                                   const int* __restrict__ bcnt,
                                                   const float* __restrict__ X,
                                                   const unsigned short* __restrict__ Wsw,
                                                   int* __restrict__ rowptr,
                                                   float* __restrict__ dinv,
                                                   unsigned* __restrict__ rec,
                                                   unsigned short* __restrict__ H) {
    __shared__ unsigned short wlds[32 * 512];   // 32 KB
    __shared__ int   cnt2[256];
    __shared__ int   cur[256];
    __shared__ float dv_s[256];
    __shared__ int   wt[4];
    __shared__ int   sbeg_s;
    const int t = threadIdx.x;
    const int lane = t & 63, wv = t >> 6;
    const int b = blockIdx.x;

    // stage W0 (independent of CSR work)
    {
        const uint4* srcp = (const uint4*)Wsw;
        uint4*       dstp = (uint4*)wlds;
#pragma unroll
        for (int i = 0; i < 8; ++i) dstp[t + i * 256] = srcp[t + i * 256];
    }

    // global bucket-base scan over bcnt (512-wide, zeros past NBUCK)
    int v0 = min(bcnt[2 * t], CAP), v1 = min(bcnt[2 * t + 1], CAP);
    int pv = v0 + v1;
    int incl = wave_incl_scan(pv, lane);
    if (lane == 63) wt[wv] = incl;
    cnt2[t] = 0;
    __syncthreads();
    {
        int pf = 0;
        for (int i = 0; i < wv; ++i) pf += wt[i];
        incl += pf;
        int eB = incl - pv;
        if (2 * t == b)     sbeg_s = eB;
        if (2 * t + 1 == b) sbeg_s = eB + v0;
    }
    __syncthreads();

    const int m = min(bcnt[b], CAP);
    const unsigned* tb = tmp + (size_t)b * CAP;
    for (int idx = t; idx < m; idx += 256)
        atomicAdd(&cnt2[tb[idx] & 255u], 1);
    __syncthreads();

    int c = cnt2[t];
    int incl2 = wave_incl_scan(c, lane);
    if (lane == 63) wt[wv] = incl2;
    __syncthreads();
    {
        int pf = 0;
        for (int i = 0; i < wv; ++i) pf += wt[i];
        incl2 += pf;
    }
    int rb = sbeg_s + (incl2 - c);
    cur[t] = rb;
    float dv = rsqrtf((float)c + 1.0f);
    dv_s[t] = dv;
    const int node = (b << 8) + t;
    if (node < N_NODES) {
        rowptr[node] = rb;
        dinv[node]   = dv;
    }
    if (b == NBUCK - 1 && t == 0) rowptr[N_NODES] = N_EDGES;
    __syncthreads();

    for (int idx = t; idx < m; idx += 256) {
        unsigned u = tb[idx];
        int pos = atomicAdd(&cur[u & 255u], 1);
        if ((unsigned)pos < (unsigned)N_EDGES)        // hard bound
            rec[pos] = (u >> 8) << 8;                 // src byte-offset
    }

    // ---- fused layer-0 GEMM: 256 rows of this block, 4 row-tiles per wave ----
    const int mq = lane & 15;
    const int q  = lane >> 4;
    const int rowbase = (b << 8) + wv * 64;

    for (int r4 = 0; r4 < 4; ++r4) {
        const int row0 = rowbase + r4 * 16;
        int r = row0 + mq;
        if (r >= N_NODES) r = N_NODES - 1;
        const float* xp = X + (size_t)r * DIM + q * 8;
        f16x8 af[4];
#pragma unroll
        for (int s = 0; s < 4; ++s) {
            float4 x0 = *(const float4*)(xp + s * 32);
            float4 x1 = *(const float4*)(xp + s * 32 + 4);
            f16x8 v;
            v[0] = (_Float16)x0.x; v[1] = (_Float16)x0.y;
            v[2] = (_Float16)x0.z; v[3] = (_Float16)x0.w;
            v[4] = (_Float16)x1.x; v[5] = (_Float16)x1.y;
            v[6] = (_Float16)x1.z; v[7] = (_Float16)x1.w;
            af[s] = v;
        }

        f32x4 acc[8];
        f32x4 z = {0.f, 0.f, 0.f, 0.f};
#pragma unroll
        for (int n = 0; n < 8; ++n) acc[n] = z;

        const unsigned short* wl = wlds + lane * 8;
#pragma unroll
        for (int s = 0; s < 4; ++s)
#pragma unroll
            for (int n = 0; n < 8; ++n) {
                f16x8 wf = *(const f16x8*)(wl + ((n * 4 + s) << 9));
                acc[n] = __builtin_amdgcn_mfma_f32_16x16x32_f16(af[s], wf, acc[n], 0, 0, 0);
            }

#pragma unroll
        for (int j = 0; j < 4; ++j) {
            int row = row0 + q * 4 + j;
            if (row < N_NODES) {
                float dvr = dv_s[row - (b << 8)];
                uint4 o;
                o.x = pack_h2(acc[0][j] * dvr, acc[1][j] * dvr);
                o.y = pack_h2(acc[2][j] * dvr, acc[3][j] * dvr);
                o.z = pack_h2(acc[4][j] * dvr, acc[5][j] * dvr);
                o.w = pack_h2(acc[6][j] * dvr, acc[7][j] * dvr);
                *(uint4*)(H + (size_t)row * DIM + mq * 8) = o;
            } else if (row < N_NODES + 32) {
                uint4 zz = make_uint4(0u, 0u, 0u, 0u);   // zero pad rows (gather sentinel)
                *(uint4*)(H + (size_t)row * DIM + mq * 8) = zz;
            }
        }
    }
}

// ---------------------------------------------------------------- fused agg + LN + ELU (+resid) + NEXT-LAYER GEMM
__global__ __launch_bounds__(256) void agg_ln_gemm(const unsigned short* __restrict__ Hh,
                                                   const unsigned short* __restrict__ xin,
                                                   const float* __restrict__ dinv,
                                                   const float* __restrict__ bias,
                                                   const float* __restrict__ g,
                                                   const float* __restrict__ be,
                                                   const int* __restrict__ rowptr,
                                                   const unsigned* __restrict__ rec,
                                                   const unsigned short* __restrict__ Wsw,
                                                   unsigned short* __restrict__ Cout,
                                                   unsigned short* __restrict__ Hout) {
    __shared__ _Float16 hl[16][136];
    const int tid  = threadIdx.x;
    const int lane = tid & 63;
    const int l16  = tid & 15;
    const int gb   = lane & 48;
    const int grp  = tid >> 4;
    const int wave = tid >> 6;
    const int node0 = blockIdx.x * 16;
    const int node = node0 + grp;
    const int beg  = rowptr[node];
    const int end  = rowptr[node + 1];
    const char* Hb8 = (const char*)Hh;
    const unsigned laneoff = (unsigned)l16 * 16;
    const unsigned sentin  = (unsigned)N_NODES << 8;

    f16x2 accA[4], accB[4], accC[4], accD[4];
    f16x2 hz = {(_Float16)0.f, (_Float16)0.f};
#pragma unroll
    for (int k = 0; k < 4; ++k) { accA[k] = hz; accB[k] = hz; accC[k] = hz; accD[k] = hz; }

    for (int e0 = beg; e0 < end; e0 += 16) {
        int cnt = min(end - e0, 16);
        unsigned sv = (l16 < cnt) ? rec[e0 + l16] : sentin;
        int cntR = (cnt + 7) & ~7;
        for (int j = 0; j < cntR; j += 8) {
            unsigned o0 = (unsigned)__shfl((int)sv, gb + j + 0, 64) + laneoff;
            unsigned o1 = (unsigned)__shfl((int)sv, gb + j + 1, 64) + laneoff;
            unsigned o2 = (unsigned)__shfl((int)sv, gb + j + 2, 64) + laneoff;
            unsigned o3 = (unsigned)__shfl((int)sv, gb + j + 3, 64) + laneoff;
            unsigned o4 = (unsigned)__shfl((int)sv, gb + j + 4, 64) + laneoff;
            unsigned o5 = (unsigned)__shfl((int)sv, gb + j + 5, 64) + laneoff;
            unsigned o6 = (unsigned)__shfl((int)sv, gb + j + 6, 64) + laneoff;
            unsigned o7 = (unsigned)__shfl((int)sv, gb + j + 7, 64) + laneoff;
            uint4 u0 = *(const uint4*)(Hb8 + o0);
            uint4 u1 = *(const uint4*)(Hb8 + o1);
            uint4 u2 = *(const uint4*)(Hb8 + o2);
            uint4 u3 = *(const uint4*)(Hb8 + o3);
            uint4 u4 = *(const uint4*)(Hb8 + o4);
            uint4 u5 = *(const uint4*)(Hb8 + o5);
            uint4 u6 = *(const uint4*)(Hb8 + o6);
            uint4 u7 = *(const uint4*)(Hb8 + o7);
            accA[0] += as_h2(u0.x); accA[1] += as_h2(u0.y); accA[2] += as_h2(u0.z); accA[3] += as_h2(u0.w);
            accB[0] += as_h2(u1.x); accB[1] += as_h2(u1.y); accB[2] += as_h2(u1.z); accB[3] += as_h2(u1.w);
            accC[0] += as_h2(u2.x); accC[1] += as_h2(u2.y); accC[2] += as_h2(u2.z); accC[3] += as_h2(u2.w);
            accD[0] += as_h2(u3.x); accD[1] += as_h2(u3.y); accD[2] += as_h2(u3.z); accD[3] += as_h2(u3.w);
            accA[0] += as_h2(u4.x); accA[1] += as_h2(u4.y); accA[2] += as_h2(u4.z); accA[3] += as_h2(u4.w);
            accB[0] += as_h2(u5.x); accB[1] += as_h2(u5.y); accB[2] += as_h2(u5.z); accB[3] += as_h2(u5.w);
            accC[0] += as_h2(u6.x); accC[1] += as_h2(u6.y); accC[2] += as_h2(u6.z); accC[3] += as_h2(u6.w);
            accD[0] += as_h2(u7.x); accD[1] += as_h2(u7.y); accD[2] += as_h2(u7.z); accD[3] += as_h2(u7.w);
        }
    }

#pragma unroll
    for (int k = 0; k < 4; ++k) accA[k] = (accA[k] + accB[k]) + (accC[k] + accD[k]);

    const float dv = dinv[node];
    const unsigned nodeoff = ((unsigned)node << 8) + laneoff;
    uint4 hv = *(const uint4*)(Hb8 + nodeoff);       // h'[node] (pre-scaled)
    const int c0 = l16 * 8;
    float4 bb0 = *(const float4*)(bias + c0);
    float4 bb1 = *(const float4*)(bias + c0 + 4);
    f16x2 h0 = as_h2(hv.x), h1 = as_h2(hv.y), h2 = as_h2(hv.z), h3 = as_h2(hv.w);

    float a[8];
    a[0] = ((float)accA[0].x + (float)h0.x) * dv + bb0.x;
    a[1] = ((float)accA[0].y + (float)h0.y) * dv + bb0.y;
    a[2] = ((float)accA[1].x + (float)h1.x) * dv + bb0.z;
    a[3] = ((float)accA[1].y + (float)h1.y) * dv + bb0.w;
    a[4] = ((float)accA[2].x + (float)h2.x) * dv + bb1.x;
    a[5] = ((float)accA[2].y + (float)h2.y) * dv + bb1.y;
    a[6] = ((float)accA[3].x + (float)h3.x) * dv + bb1.z;
    a[7] = ((float)accA[3].y + (float)h3.y) * dv + bb1.w;

    float s1 = 0.f, s2 = 0.f;
#pragma unroll
    for (int i = 0; i < 8; ++i) { s1 += a[i]; s2 += a[i] * a[i]; }
#pragma unroll
    for (int mk = 1; mk <= 8; mk <<= 1) {
        s1 += __shfl_xor(s1, mk, 64);
        s2 += __shfl_xor(s2, mk, 64);
    }
    float mean = s1 * (1.0f / 128.0f);
    float var  = s2 * (1.0f / 128.0f) - mean * mean;
    float rr   = rsqrtf(var + 1e-5f);

    float4 gg0 = *(const float4*)(g + c0);
    float4 gg1 = *(const float4*)(g + c0 + 4);
    float4 ee0 = *(const float4*)(be + c0);
    float4 ee1 = *(const float4*)(be + c0 + 4);

    float r[8];
    r[0] = (a[0] - mean) * rr * gg0.x + ee0.x;
    r[1] = (a[1] - mean) * rr * gg0.y + ee0.y;
    r[2] = (a[2] - mean) * rr * gg0.z + ee0.z;
    r[3] = (a[3] - mean) * rr * gg0.w + ee0.w;
    r[4] = (a[4] - mean) * rr * gg1.x + ee1.x;
    r[5] = (a[5] - mean) * rr * gg1.y + ee1.y;
    r[6] = (a[6] - mean) * rr * gg1.z + ee1.z;
    r[7] = (a[7] - mean) * rr * gg1.w + ee1.w;
#pragma unroll
    for (int i = 0; i < 8; ++i) r[i] = r[i] > 0.0f ? r[i] : expm1f(r[i]);

    if (xin) {
        uint4 xv = *(const uint4*)((const char*)xin + nodeoff);
        f16x2 x0 = as_h2(xv.x), x1 = as_h2(xv.y), x2 = as_h2(xv.z), x3 = as_h2(xv.w);
        r[0] += (float)x0.x; r[1] += (float)x0.y;
        r[2] += (float)x1.x; r[3] += (float)x1.y;
        r[4] += (float)x2.x; r[5] += (float)x2.y;
        r[6] += (float)x3.x; r[7] += (float)x3.y;
    }

    uint4 o;
    o.x = pack_h2(r[0], r[1]);
    o.y = pack_h2(r[2], r[3]);
    o.z = pack_h2(r[4], r[5]);
    o.w = pack_h2(r[6], r[7]);
    *(uint4*)((char*)Cout + nodeoff) = o;        // residual source for next layer
    *(uint4*)&hl[grp][l16 * 8] = o;              // GEMM A-tile
    __syncthreads();

    // ---- next-layer GEMM: 16x128 tile, 2 col-tiles per wave ----
    {
        const int m = lane & 15;
        const int q = lane >> 4;

        f16x8 af[4];
#pragma unroll
        for (int s = 0; s < 4; ++s)
            af[s] = *(const f16x8*)&hl[m][q * 8 + s * 32];

        f32x4 acc2[2];
        f32x4 z = {0.f, 0.f, 0.f, 0.f};
        acc2[0] = z; acc2[1] = z;

#pragma unroll
        for (int s = 0; s < 4; ++s)
#pragma unroll
            for (int p = 0; p < 2; ++p) {
                f16x8 wfv = *(const f16x8*)(Wsw + (((2 * wave + p) * 4 + s) << 9) + lane * 8);
                acc2[p] = __builtin_amdgcn_mfma_f32_16x16x32_f16(af[s], wfv, acc2[p], 0, 0, 0);
            }

#pragma unroll
        for (int j = 0; j < 4; ++j) {
            int row = node0 + q * 4 + j;
            float dv2 = dinv[row];
            *(unsigned*)((char*)Hout + ((unsigned)row << 8) + ((unsigned)(m * 8 + 2 * wave) << 1)) =
                pack_h2(acc2[0][j] * dv2, acc2[1][j] * dv2);
        }
    }
}

// ---------------------------------------------------------------- layer-2 agg + LN + ELU + residual + CLASSIFIER (fused)
__global__ __launch_bounds__(256) void agg_ln_cls(const unsigned short* __restrict__ Hh,
                                                  const unsigned short* __restrict__ xin,
                                                  const float* __restrict__ dinv,
                                                  const float* __restrict__ bias,
                                                  const float* __restrict__ g,
                                                  const float* __restrict__ be,
                                                  const int* __restrict__ rowptr,
                                                  const unsigned* __restrict__ rec,
                                                  const unsigned short* __restrict__ Wcsw,
                                                  const float* __restrict__ bc,
                                                  float* __restrict__ out) {
    __shared__ _Float16 hl[16][136];
    const int tid  = threadIdx.x;
    const int lane = tid & 63;
    const int l16  = tid & 15;
    const int gb   = lane & 48;
    const int grp  = tid >> 4;
    const int node0 = blockIdx.x * 16;
    const int node = node0 + grp;
    const int beg  = rowptr[node];
    const int end  = rowptr[node + 1];
    const char* Hb8 = (const char*)Hh;
    const unsigned laneoff = (unsigned)l16 * 16;
    const unsigned sentin  = (unsigned)N_NODES << 8;

    f16x2 accA[4], accB[4], accC[4], accD[4];
    f16x2 hz = {(_Float16)0.f, (_Float16)0.f};
#pragma unroll
    for (int k = 0; k < 4; ++k) { accA[k] = hz; accB[k] = hz; accC[k] = hz; accD[k] = hz; }

    for (int e0 = beg; e0 < end; e0 += 16) {
        int cnt = min(end - e0, 16);
        unsigned sv = (l16 < cnt) ? rec[e0 + l16] : sentin;
        int cntR = (cnt + 7) & ~7;
        for (int j = 0; j < cntR; j += 8) {
            unsigned o0 = (unsigned)__shfl((int)sv, gb + j + 0, 64) + laneoff;
            unsigned o1 = (unsigned)__shfl((int)sv, gb + j + 1, 64) + laneoff;
            unsigned o2 = (unsigned)__shfl((int)sv, gb + j + 2, 64) + laneoff;
            unsigned o3 = (unsigned)__shfl((int)sv, gb + j + 3, 64) + laneoff;
            unsigned o4 = (unsigned)__shfl((int)sv, gb + j + 4, 64) + laneoff;
            unsigned o5 = (unsigned)__shfl((int)sv, gb + j + 5, 64) + laneoff;
            unsigned o6 = (unsigned)__shfl((int)sv, gb + j + 6, 64) + laneoff;
            unsigned o7 = (unsigned)__shfl((int)sv, gb + j + 7, 64) + laneoff;
            uint4 u0 = *(const uint4*)(Hb8 + o0);
            uint4 u1 = *(const uint4*)(Hb8 + o1);
            uint4 u2 = *(const uint4*)(Hb8 + o2);
            uint4 u3 = *(const uint4*)(Hb8 + o3);
            uint4 u4 = *(const uint4*)(Hb8 + o4);
            uint4 u5 = *(const uint4*)(Hb8 + o5);
            uint4 u6 = *(const uint4*)(Hb8 + o6);
            uint4 u7 = *(const uint4*)(Hb8 + o7);
            accA[0] += as_h2(u0.x); accA[1] += as_h2(u0.y); accA[2] += as_h2(u0.z); accA[3] += as_h2(u0.w);
            accB[0] += as_h2(u1.x); accB[1] += as_h2(u1.y); accB[2] += as_h2(u1.z); accB[3] += as_h2(u1.w);
            accC[0] += as_h2(u2.x); accC[1] += as_h2(u2.y); accC[2] += as_h2(u2.z); accC[3] += as_h2(u2.w);
            accD[0] += as_h2(u3.x); accD[1] += as_h2(u3.y); accD[2] += as_h2(u3.z); accD[3] += as_h2(u3.w);
            accA[0] += as_h2(u4.x); accA[1] += as_h2(u4.y); accA[2] += as_h2(u4.z); accA[3] += as_h2(u4.w);
            accB[0] += as_h2(u5.x); accB[1] += as_h2(u5.y); accB[2] += as_h2(u5.z); accB[3] += as_h2(u5.w);
            accC[0] += as_h2(u6.x); accC[1] += as_h2(u6.y); accC[2] += as_h2(u6.z); accC[3] += as_h2(u6.w);
            accD[0] += as_h2(u7.x); accD[1] += as_h2(u7.y); accD[2] += as_h2(u7.z); accD[3] += as_h2(u7.w);
        }
    }

#pragma unroll
    for (int k = 0; k < 4; ++k) accA[k] = (accA[k] + accB[k]) + (accC[k] + accD[k]);

    const float dv = dinv[node];
    const unsigned nodeoff = ((unsigned)node << 8) + laneoff;
    uint4 hv = *(const uint4*)(Hb8 + nodeoff);
    const int c0 = l16 * 8;
    float4 bb0 = *(const float4*)(bias + c0);
    float4 bb1 = *(const float4*)(bias + c0 + 4);
    f16x2 h0 = as_h2(hv.x), h1 = as_h2(hv.y), h2 = as_h2(hv.z), h3 = as_h2(hv.w);

    float a[8];
    a[0] = ((float)accA[0].x + (float)h0.x) * dv + bb0.x;
    a[1] = ((float)accA[0].y + (float)h0.y) * dv + bb0.y;
    a[2] = ((float)accA[1].x + (float)h1.x) * dv + bb0.z;
    a[3] = ((float)accA[1].y + (float)h1.y) * dv + bb0.w;
    a[4] = ((float)accA[2].x + (float)h2.x) * dv + bb1.x;
    a[5] = ((float)accA[2].y + (float)h2.y) * dv + bb1.y;
    a[6] = ((float)accA[3].x + (float)h3.x) * dv + bb1.z;
    a[7] = ((float)accA[3].y + (float)h3.y) * dv + bb1.w;

    float s1 = 0.f, s2 = 0.f;
#pragma unroll
    for (int i = 0; i < 8; ++i) { s1 += a[i]; s2 += a[i] * a[i]; }
#pragma unroll
    for (int mk = 1; mk <= 8; mk <<= 1) {
        s1 += __shfl_xor(s1, mk, 64);
        s2 += __shfl_xor(s2, mk, 64);
    }
    float mean = s1 * (1.0f / 128.0f);
    float var  = s2 * (1.0f / 128.0f) - mean * mean;
    float rr   = rsqrtf(var + 1e-5f);

    float4 gg0 = *(const float4*)(g + c0);
    float4 gg1 = *(const float4*)(g + c0 + 4);
    float4 ee0 = *(const float4*)(be + c0);
    float4 ee1 = *(const float4*)(be + c0 + 4);

    float r[8];
    r[0] = (a[0] - mean) * rr * gg0.x + ee0.x;
    r[1] = (a[1] - mean) * rr * gg0.y + ee0.y;
    r[2] = (a[2] - mean) * rr * gg0.z + ee0.z;
    r[3] = (a[3] - mean) * rr * gg0.w + ee0.w;
    r[4] = (a[4] - mean) * rr * gg1.x + ee1.x;
    r[5] = (a[5] - mean) * rr * gg1.y + ee1.y;
    r[6] = (a[6] - mean) * rr * gg1.z + ee1.z;
    r[7] = (a[7] - mean) * rr * gg1.w + ee1.w;
#pragma unroll
    for (int i = 0; i < 8; ++i) r[i] = r[i] > 0.0f ? r[i] : expm1f(r[i]);

    if (xin) {
        uint4 xv = *(const uint4*)((const char*)xin + nodeoff);
        f16x2 x0 = as_h2(xv.x), x1 = as_h2(xv.y), x2 = as_h2(xv.z), x3 = as_h2(xv.w);
        r[0] += (float)x0.x; r[1] += (float)x0.y;
        r[2] += (float)x1.x; r[3] += (float)x1.y;
        r[4] += (float)x2.x; r[5] += (float)x2.y;
        r[6] += (float)x3.x; r[7] += (float)x3.y;
    }

    uint4 o;
    o.x = pack_h2(r[0], r[1]);
    o.y = pack_h2(r[2], r[3]);
    o.z = pack_h2(r[4], r[5]);
    o.w = pack_h2(r[6], r[7]);
    *(uint4*)&hl[grp][l16 * 8] = o;
    __syncthreads();

    if (tid < 64) {
        const int m = lane & 15;
        const int q = lane >> 4;

        f16x8 wf[12];
#pragma unroll
        for (int f = 0; f < 12; ++f)
            wf[f] = *(const f16x8*)(Wcsw + (f << 9) + lane * 8);

        f16x8 af[4];
#pragma unroll
        for (int s = 0; s < 4; ++s)
            af[s] = *(const f16x8*)&hl[m][q * 8 + s * 32];

        f32x4 acc[3];
        f32x4 z = {0.f, 0.f, 0.f, 0.f};
#pragma unroll
        for (int n = 0; n < 3; ++n) acc[n] = z;

#pragma unroll
        for (int s = 0; s < 4; ++s)
#pragma unroll
            for (int n = 0; n < 3; ++n)
                acc[n] = __builtin_amdgcn_mfma_f32_16x16x32_f16(af[s], wf[n * 4 + s], acc[n], 0, 0, 0);

#pragma unroll
        for (int j = 0; j < 4; ++j) {
            int row = node0 + q * 4 + j;
#pragma unroll
            for (int n = 0; n < 3; ++n) {
                int c = 3 * m + n;
                if (c < NCLS)
                    out[(size_t)row * NCLS + c] = acc[n][j] + bc[c];
            }
        }
    }
}

// ---------------------------------------------------------------- launch
extern "C" void kernel_launch(void* const* d_in, const int* in_sizes, int n_in,
                              void* d_out, int out_size, void* d_ws, size_t ws_size,
                              hipStream_t stream) {
    const float* x  = (const float*)d_in[0];
    const int*   ei = (const int*)d_in[1];
    const float* W[3]  = {(const float*)d_in[2], (const float*)d_in[6], (const float*)d_in[10]};
    const float* b[3]  = {(const float*)d_in[3], (const float*)d_in[7], (const float*)d_in[11]};
    const float* g[3]  = {(const float*)d_in[4], (const float*)d_in[8], (const float*)d_in[12]};
    const float* be[3] = {(const float*)d_in[5], (const float*)d_in[9], (const float*)d_in[13]};
    const float* Wc = (const float*)d_in[14];
    const float* bc = (const float*)d_in[15];
    float* out = (float*)d_out;

    char* ws = (char*)d_ws;
    const size_t NP = 400128;  // padded (N+1)*4 bytes
    float* dinv   = (float*)(ws);
    int*   rowptr = (int*)  (ws + NP);
    int*   bcnt   = (int*)  (ws + 2 * NP);            // 512 ints
    unsigned* rec = (unsigned*)(ws + 2 * NP + 4096);
    unsigned short* H1 = (unsigned short*)(ws + 2 * NP + 4096 + (size_t)N_EDGES * 8);
    unsigned short* H2 = H1 + (size_t)(N_NODES + 64) * DIM;   // both H buffers have zero-pad rows
    unsigned short* Ch = H2 + (size_t)(N_NODES + 64) * DIM;
    unsigned short* Wsw0 = Ch + (size_t)N_NODES * DIM;
    unsigned short* Wsw1 = Wsw0 + DIM * DIM;
    unsigned short* Wsw2 = Wsw1 + DIM * DIM;
    unsigned short* Wcsw = Wsw2 + DIM * DIM;   // 12*512 shorts
    unsigned* tmp = (unsigned*)Ch;             // aliases Ch (12.8 MB < 25.6 MB); dead before agg0 writes Ch

    // ---- zero bcnt ----
    hipMemsetAsync(bcnt, 0, 2048, stream);

    // ---- setup + p1 (fixed-cap bucketing, ei read once) ----
    setup_p1<<<217 + NBUCK, 256, 0, stream>>>(W[0], W[1], W[2], Wc, ei,
                                              Wsw0, Wsw1, Wsw2, Wcsw, bcnt, tmp, H2);

    // ---- p2 CSR + fused layer-0 GEMM ----
    csr_p2_gemm<<<NBUCK, 256, 0, stream>>>(tmp, bcnt, x, Wsw0, rowptr, dinv, rec, H1);

    const int agg_grid = N_NODES / 16;            // 6250 (16 nodes/block, quarter-wave each)

    // layer 0 agg + layer 1 GEMM: gather H1 -> Ch (residual), GEMM -> H2
    agg_ln_gemm<<<agg_grid, 256, 0, stream>>>(H1, nullptr, dinv, b[0], g[0], be[0],
                                              rowptr, rec, Wsw1, Ch, H2);

    // layer 1 agg + layer 2 GEMM: gather H2, resid Ch -> Ch (in-place), GEMM -> H1
    agg_ln_gemm<<<agg_grid, 256, 0, stream>>>(H2, Ch, dinv, b[1], g[1], be[1],
                                              rowptr, rec, Wsw2, Ch, H1);

    // layer 2 agg + classifier: gather H1, resid Ch -> logits
    agg_ln_cls<<<agg_grid, 256, 0, stream>>>(H1, Ch, dinv, b[2], g[2], be[2],
                                             rowptr, rec, Wcsw, bc, out);
}